// Round 1
// baseline (725.136 us; speedup 1.0000x reference)
//
#include <hip/hip_runtime.h>
#include <math.h>

#define LM 512
#define TLEN 1024
#define TINY_F 1.17549435e-38f

// d_ws float layout (total 17920 floats = 71680 B)
#define OFF_ENTER 0
#define OFF_MTM   512
#define OFF_I2M   1024
#define OFF_DTM   1536
#define OFF_WC    2048
#define OFF_MC    2560
#define OFF_M2I   3072
#define OFF_I2I   3584
#define OFF_M2E   4096
#define OFF_INS   4608
#define OFF_SC    4640
#define OFF_EMB   5120

// ---------------------------------------------------------------------------
// Setup: build softmaxed params + rank-1 skip-chain coefficients + transposed
// emission table into d_ws. Runs once per launch (1 block, ~few us).
// ---------------------------------------------------------------------------
__global__ __launch_bounds__(512) void hmm_setup(
    const float* __restrict__ em, const float* __restrict__ ins,
    const float* __restrict__ flank, const float* __restrict__ btm,
    const float* __restrict__ m2e, const float* __restrict__ mtm,
    const float* __restrict__ m2i, const float* __restrict__ i2m,
    const float* __restrict__ i2i, const float* __restrict__ mtd,
    const float* __restrict__ dtm, const float* __restrict__ dtd,
    const float* __restrict__ lfl, const float* __restrict__ lfe,
    const float* __restrict__ e2u, const float* __restrict__ e2r,
    const float* __restrict__ e2t, float* __restrict__ P)
{
    __shared__ float beginp[513];
    __shared__ float mtdp[512], dtmp[512], dtdp[512], cplog[512];
    __shared__ float mtmp[512], m2ip[512], m2ep[512], i2mp[512], i2ip[512];
    __shared__ float rbuf[512];
    const int j = threadIdx.x;

    // begin softmax over 513 = concat(btm[512], mtd[0])
    float eb = expf(btm[j]);
    rbuf[j] = eb;
    __syncthreads();
    for (int s = 256; s > 0; s >>= 1) {
        if (j < s) rbuf[j] += rbuf[j + s];
        __syncthreads();
    }
    float e512 = expf(mtd[0]);
    float tot = rbuf[0] + e512;
    beginp[j] = eb / tot;
    if (j == 0) beginp[512] = e512 / tot;

    if (j < 511) {
        float a = expf(mtm[j]), b = expf(m2i[j]), c = expf(m2e[j]), d = expf(mtd[j + 1]);
        float s = a + b + c + d;
        mtmp[j] = a / s; m2ip[j] = b / s; m2ep[j] = c / s; mtdp[j + 1] = d / s;
        float ia = expf(i2m[j]), ib = expf(i2i[j]); s = ia + ib;
        i2mp[j] = ia / s; i2ip[j] = ib / s;
        float da = expf(dtm[j]), db = expf(dtd[j]); s = da + db;
        dtmp[j] = da / s; dtdp[j] = db / s;
    }
    if (j == 511) dtmp[511] = 1.0f;
    __syncthreads();

    if (j == 0) {
        mtdp[0] = beginp[512];
        float c = 0.f; cplog[0] = 0.f;
        for (int i = 0; i < 511; ++i) { c += logf(dtdp[i]); cplog[i + 1] = c; }
        // insert emission softmax
        float sm = 0.f;
        for (int s = 0; s < 25; ++s) sm += expf(ins[s]);
        for (int s = 0; s < 25; ++s) P[OFF_INS + s] = expf(ins[s]) / sm;
        // scalars
        float fl = expf(lfl[0]), fe = expf(lfe[0]); float fs = fl + fe;
        float floop = fl / fs, fexit = fe / fs;
        float eu = expf(e2u[0]), er = expf(e2r[0]), et = expf(e2t[0]);
        float es = eu + er + et; float ep0 = eu / es, ep1 = er / es;
        float p0 = 1.0f / (1.0f + expf(-flank[0]));
        float be = mtdp[0] * expf(cplog[511]) * dtmp[511]; // underflows to 0, same as ref fp32
        P[OFF_SC + 0] = floop;
        P[OFF_SC + 1] = fexit;
        P[OFF_SC + 2] = p0;
        P[OFF_SC + 3] = fexit * be * ep0;
        P[OFF_SC + 4] = fexit * be * ep1;
        P[OFF_SC + 5] = ep0;
        P[OFF_SC + 6] = ep1;
        P[OFF_SC + 7] = (1.0f - p0) * be * ep0;
        P[OFF_SC + 8] = (1.0f - p0) * be * ep1;
        P[OFF_SC + 9] = 1.0f - p0;
    }
    __syncthreads();

    // per-state (j = 0..511) padded coefficient arrays
    float en = beginp[j];
    if (j >= 1) en += mtdp[0] * expf(cplog[j - 1]) * dtmp[j - 1];
    P[OFF_ENTER + j] = en;
    P[OFF_MTM + j] = (j >= 1) ? mtmp[j - 1] : 0.f;
    P[OFF_I2M + j] = (j >= 1) ? i2mp[j - 1] : 0.f;
    P[OFF_DTM + j] = (j >= 1) ? dtmp[j - 1] : 0.f;
    P[OFF_WC  + j] = (j >= 1) ? mtdp[j]     : 0.f;
    P[OFF_MC  + j] = (j >= 1) ? dtdp[j - 1] : 0.f;
    P[OFF_M2I + j] = (j < 511) ? m2ip[j] : 0.f;
    P[OFF_I2I + j] = (j < 511) ? i2ip[j] : 0.f;
    P[OFF_M2E + j] = (j < 511)
        ? (m2ep[j] + mtdp[j + 1] * expf(cplog[511] - cplog[j + 1]))
        : 1.0f;

    // match emission softmax row j -> transposed table embT[sym][j]
    {
        const float* row = em + j * 25;
        float mx = row[0];
        for (int s = 1; s < 25; ++s) mx = fmaxf(mx, row[s]);
        float sm = 0.f;
        for (int s = 0; s < 25; ++s) sm += expf(row[s] - mx);
        float inv = 1.0f / sm;
        for (int s = 0; s < 25; ++s) P[OFF_EMB + s * 512 + j] = expf(row[s] - mx) * inv;
    }
}

// ---------------------------------------------------------------------------
// Forward: one wave per batch element. 8 match + 8 insert states per lane.
// Rank-1 delete-chain handled by an affine (Q = Q*m + w) Kogge-Stone scan.
// Deferred normalization every 8 steps.
// ---------------------------------------------------------------------------
__global__ __launch_bounds__(64, 1) void hmm_forward(
    const int* __restrict__ seq, const float* __restrict__ P,
    float* __restrict__ out)
{
    const int lane = threadIdx.x;
    const int b = blockIdx.x;
    const int base = lane * 8;

    float enter_[8], mtm_[8], i2m_[8], dtm_[8], wC_[8], mC_[8], m2i_[8], i2i_[8], m2e_[8];
#pragma unroll
    for (int e = 0; e < 8; ++e) {
        enter_[e] = P[OFF_ENTER + base + e];
        mtm_[e]   = P[OFF_MTM + base + e];
        i2m_[e]   = P[OFF_I2M + base + e];
        dtm_[e]   = P[OFF_DTM + base + e];
        wC_[e]    = P[OFF_WC + base + e];
        mC_[e]    = P[OFF_MC + base + e];
        m2i_[e]   = P[OFF_M2I + base + e];
        i2i_[e]   = P[OFF_I2I + base + e];
        m2e_[e]   = P[OFF_M2E + base + e];
    }
    const float floop = P[OFF_SC + 0], fexit = P[OFF_SC + 1], p0 = P[OFF_SC + 2];
    const float c1ep0 = P[OFF_SC + 3], c1ep1 = P[OFF_SC + 4];
    const float ep0 = P[OFF_SC + 5], ep1 = P[OFF_SC + 6];
    const float U0 = P[OFF_SC + 7], RF0 = P[OFF_SC + 8], omp0 = P[OFF_SC + 9];
    const float* embT = P + OFF_EMB;
    const float* insB = P + OFF_INS;
    const int* sq = seq + b * TLEN;

    int sym = sq[0];
    float EmC[8], EiC;
    {
        const float4* c0 = (const float4*)(embT + sym * 512 + base);
        float4 x = c0[0], y = c0[1];
        EmC[0] = x.x; EmC[1] = x.y; EmC[2] = x.z; EmC[3] = x.w;
        EmC[4] = y.x; EmC[5] = y.y; EmC[6] = y.z; EmC[7] = y.w;
        EiC = insB[sym];
    }

    float am[8], ai[8];
#pragma unroll
    for (int e = 0; e < 8; ++e) { am[e] = EmC[e] * (omp0 * enter_[e]); ai[e] = 0.f; }
    float f0 = p0 * EiC;
    float U  = U0 * EiC;
    float RF = RF0 * EiC;
    float ll = 0.f;

    // prefetch pipeline: E-column one step ahead, symbol two ahead
    int symN = sq[1];
    float EmN[8], EiN;
    {
        const float4* c0 = (const float4*)(embT + symN * 512 + base);
        float4 x = c0[0], y = c0[1];
        EmN[0] = x.x; EmN[1] = x.y; EmN[2] = x.z; EmN[3] = x.w;
        EmN[4] = y.x; EmN[5] = y.y; EmN[6] = y.z; EmN[7] = y.w;
        EiN = insB[symN];
    }
    int symNN = sq[2];

    for (int t = 1; t < TLEN; ++t) {
        // rotate prefetch: EmC <- EmN, issue loads for t+1
#pragma unroll
        for (int e = 0; e < 8; ++e) EmC[e] = EmN[e];
        EiC = EiN;
        {
            const float4* c0 = (const float4*)(embT + symNN * 512 + base);
            float4 x = c0[0], y = c0[1];
            EmN[0] = x.x; EmN[1] = x.y; EmN[2] = x.z; EmN[3] = x.w;
            EmN[4] = y.x; EmN[5] = y.y; EmN[6] = y.z; EmN[7] = y.w;
            EiN = insB[symNN];
        }
        int tn = t + 2; if (tn > TLEN - 1) tn = TLEN - 1;
        symNN = sq[tn];

        // neighbor-lane shifts of previous alpha
        float amL = __shfl_up(am[7], 1);
        float aiL = __shfl_up(ai[7], 1);

        // local affine prefix for Q[t] = Q[t-1]*dtd[t-1] + a_m[t-1]*mtd[t]
        float Apre[8], Mpre[8];
        Apre[0] = amL * wC_[0];
        Mpre[0] = mC_[0];
#pragma unroll
        for (int e = 1; e < 8; ++e) {
            Apre[e] = fmaf(Apre[e - 1], mC_[e], am[e - 1] * wC_[e]);
            Mpre[e] = Mpre[e - 1] * mC_[e];
        }
        // cross-lane affine inclusive scan (Kogge-Stone, 6 steps)
        float As = Apre[7], Ms = Mpre[7];
#pragma unroll
        for (int d = 1; d < 64; d <<= 1) {
            float Ao = __shfl_up(As, d);
            float Mo = __shfl_up(Ms, d);
            if (lane < d) { Ao = 0.f; Mo = 1.f; }
            As = fmaf(Ms, Ao, As);
            Ms = Ms * Mo;
        }
        float carry = __shfl_up(As, 1);
        if (lane == 0) carry = 0.f;

        // D = sum(a_m * m2e_tot) -> feeds U / RF
        float dsum = 0.f;
#pragma unroll
        for (int e = 0; e < 8; ++e) dsum = fmaf(am[e], m2e_[e], dsum);
#pragma unroll
        for (int d = 1; d < 64; d <<= 1) dsum += __shfl_xor(dsum, d);

        // scalar states (replicated across lanes)
        float aFU = (f0 + U) * fexit;
        float nf0 = EiC * (f0 * floop);
        float nU  = EiC * (fmaf(f0, c1ep0, U * (floop + c1ep0)) + dsum * ep0);
        float nRF = EiC * ((f0 + U) * c1ep1 + dsum * ep1 + RF * floop);
        f0 = nf0; U = nU; RF = nRF;

        // insert -> match inflow (needs old ai)
        float iin[8];
        iin[0] = aiL * i2m_[0];
#pragma unroll
        for (int e = 1; e < 8; ++e) iin[e] = ai[e - 1] * i2m_[e];
        // insert update (old am, old ai)
#pragma unroll
        for (int e = 0; e < 8; ++e) ai[e] = EiC * fmaf(am[e], m2i_[e], ai[e] * i2i_[e]);
        // match update, descending so old am[e-1] survives
#pragma unroll
        for (int e = 7; e >= 1; --e) {
            float Qp = fmaf(Mpre[e - 1], carry, Apre[e - 1]);
            float infl = fmaf(aFU, enter_[e],
                         fmaf(am[e - 1], mtm_[e],
                         fmaf(dtm_[e], Qp, iin[e])));
            am[e] = EmC[e] * infl;
        }
        {
            float infl = fmaf(aFU, enter_[0],
                         fmaf(amL, mtm_[0],
                         fmaf(dtm_[0], carry, iin[0])));
            am[0] = EmC[0] * infl;
        }

        // deferred normalization every 8 steps + final step
        if ((t & 7) == 0 || t == TLEN - 1) {
            float s = f0 + U + RF;
#pragma unroll
            for (int e = 0; e < 8; ++e) s += am[e] + ai[e];
#pragma unroll
            for (int d = 1; d < 64; d <<= 1) s += __shfl_xor(s, d);
            s += TINY_F;
            ll += logf(s);
            float inv = 1.0f / s;
#pragma unroll
            for (int e = 0; e < 8; ++e) { am[e] *= inv; ai[e] *= inv; }
            f0 *= inv; U *= inv; RF *= inv;
        }
    }
    if (lane == 0) out[b] = ll;
}

extern "C" void kernel_launch(void* const* d_in, const int* in_sizes, int n_in,
                              void* d_out, int out_size, void* d_ws, size_t ws_size,
                              hipStream_t stream) {
    const int*   seq   = (const int*)d_in[0];
    const float* em    = (const float*)d_in[1];
    const float* ins   = (const float*)d_in[2];
    const float* flank = (const float*)d_in[3];
    const float* btm   = (const float*)d_in[4];
    const float* m2e   = (const float*)d_in[5];
    const float* mtm   = (const float*)d_in[6];
    const float* m2i   = (const float*)d_in[7];
    const float* i2m   = (const float*)d_in[8];
    const float* i2i   = (const float*)d_in[9];
    const float* mtd   = (const float*)d_in[10];
    const float* dtm   = (const float*)d_in[11];
    const float* dtd   = (const float*)d_in[12];
    const float* lfl   = (const float*)d_in[13];
    const float* lfe   = (const float*)d_in[14];
    const float* e2u   = (const float*)d_in[15];
    const float* e2r   = (const float*)d_in[16];
    const float* e2t   = (const float*)d_in[17];
    float* P = (float*)d_ws;  // needs 71680 B
    float* out = (float*)d_out;

    hipLaunchKernelGGL(hmm_setup, dim3(1), dim3(512), 0, stream,
        em, ins, flank, btm, m2e, mtm, m2i, i2m, i2i, mtd, dtm, dtd,
        lfl, lfe, e2u, e2r, e2t, P);
    hipLaunchKernelGGL(hmm_forward, dim3(128), dim3(64), 0, stream, seq, P, out);
}

// Round 2
// 383.329 us; speedup vs baseline: 1.8917x; 1.8917x over previous
//
#include <hip/hip_runtime.h>
#include <math.h>

#define LM 512
#define TLEN 1024
#define TINY_F 1.17549435e-38f

// d_ws float layout (total 17920 floats = 71680 B)
#define OFF_ENTER 0
#define OFF_MTM   512
#define OFF_I2M   1024
#define OFF_DTM   1536
#define OFF_WC    2048
#define OFF_MC    2560
#define OFF_M2I   3072
#define OFF_I2I   3584
#define OFF_M2E   4096
#define OFF_INS   4608
#define OFF_SC    4640
#define OFF_EMB   5120

// ---------------------------------------------------------------------------
// DPP helpers (CDNA keeps row_shr / wave_shr / row_bcast). Pure VALU lane
// moves: ~2-4 cyc vs ~60-90 cyc for ds_bpermute-based __shfl.
// ---------------------------------------------------------------------------
template<int Ctrl, int RowMask>
__device__ __forceinline__ float fdpp(float oldv, float src) {
    int r = __builtin_amdgcn_update_dpp(
        __builtin_bit_cast(int, oldv), __builtin_bit_cast(int, src),
        Ctrl, RowMask, 0xF, false);
    return __builtin_bit_cast(float, r);
}
// ctrl encodings: row_shr:N = 0x110|N, wave_shr:1 = 0x138,
//                 row_bcast:15 = 0x142, row_bcast:31 = 0x143

__device__ __forceinline__ float bcast63(float v) {
    return __builtin_bit_cast(float,
        __builtin_amdgcn_readlane(__builtin_bit_cast(int, v), 63));
}

// sum across 64 lanes; total lands in lane 63
__device__ __forceinline__ float wave_sum_to63(float v) {
    v += fdpp<0x111, 0xF>(0.f, v);
    v += fdpp<0x112, 0xF>(0.f, v);
    v += fdpp<0x114, 0xF>(0.f, v);
    v += fdpp<0x118, 0xF>(0.f, v);
    v += fdpp<0x142, 0xA>(0.f, v);
    v += fdpp<0x143, 0xC>(0.f, v);
    return v;
}

// ---------------------------------------------------------------------------
// Setup: softmaxed params + rank-1 skip-chain coefficients + interleaved
// transposed emission table. 1 block x 512 threads; cplog prefix is now a
// parallel Hillis-Steele scan (round-1 serial loop on thread 0 cost ~100us).
// ---------------------------------------------------------------------------
__global__ __launch_bounds__(512) void hmm_setup(
    const float* __restrict__ em, const float* __restrict__ ins,
    const float* __restrict__ flank, const float* __restrict__ btm,
    const float* __restrict__ m2e, const float* __restrict__ mtm,
    const float* __restrict__ m2i, const float* __restrict__ i2m,
    const float* __restrict__ i2i, const float* __restrict__ mtd,
    const float* __restrict__ dtm, const float* __restrict__ dtd,
    const float* __restrict__ lfl, const float* __restrict__ lfe,
    const float* __restrict__ e2u, const float* __restrict__ e2r,
    const float* __restrict__ e2t, float* __restrict__ P)
{
    __shared__ float beginp[513];
    __shared__ float mtdp[512], dtmp[512], dtdp[512], cplog[512];
    __shared__ float mtmp[512], m2ip[512], m2ep[512], i2mp[512], i2ip[512];
    __shared__ float rbuf[512], rbuf2[512];
    const int j = threadIdx.x;

    // begin softmax over 513 = concat(btm[512], mtd[0])
    float eb = expf(btm[j]);
    rbuf[j] = eb;
    __syncthreads();
    for (int s = 256; s > 0; s >>= 1) {
        if (j < s) rbuf[j] += rbuf[j + s];
        __syncthreads();
    }
    float e512 = expf(mtd[0]);
    float tot = rbuf[0] + e512;
    beginp[j] = eb / tot;
    if (j == 0) { beginp[512] = e512 / tot; mtdp[0] = e512 / tot; }

    if (j < 511) {
        float a = expf(mtm[j]), b = expf(m2i[j]), c = expf(m2e[j]), d = expf(mtd[j + 1]);
        float s = a + b + c + d;
        mtmp[j] = a / s; m2ip[j] = b / s; m2ep[j] = c / s; mtdp[j + 1] = d / s;
        float ia = expf(i2m[j]), ib = expf(i2i[j]); s = ia + ib;
        i2mp[j] = ia / s; i2ip[j] = ib / s;
        float da = expf(dtm[j]), db = expf(dtd[j]); s = da + db;
        dtmp[j] = da / s; dtdp[j] = db / s;
    }
    if (j == 511) dtmp[511] = 1.0f;
    __syncthreads();

    // parallel prefix: cplog[j] = sum_{i<j} log(dtdp[i])
    {
        float lw = (j >= 1) ? logf(dtdp[j - 1]) : 0.f;
        rbuf[j] = lw;
        __syncthreads();
        float* bufs[2] = { rbuf, rbuf2 };
        int cur = 0;
        for (int off = 1; off < 512; off <<= 1) {
            float v = bufs[cur][j];
            if (j >= off) v += bufs[cur][j - off];
            bufs[cur ^ 1][j] = v;
            cur ^= 1;
            __syncthreads();
        }
        cplog[j] = bufs[cur][j];
    }
    __syncthreads();

    if (j == 0) {
        // insert emission softmax
        float sm = 0.f;
        for (int s = 0; s < 25; ++s) sm += expf(ins[s]);
        for (int s = 0; s < 25; ++s) P[OFF_INS + s] = expf(ins[s]) / sm;
        // scalars
        float fl = expf(lfl[0]), fe = expf(lfe[0]); float fs = fl + fe;
        float floop = fl / fs, fexit = fe / fs;
        float eu = expf(e2u[0]), er = expf(e2r[0]), et = expf(e2t[0]);
        float es = eu + er + et; float ep0 = eu / es, ep1 = er / es;
        float p0 = 1.0f / (1.0f + expf(-flank[0]));
        float be = mtdp[0] * expf(cplog[511]) * dtmp[511]; // underflows to 0 like ref fp32
        P[OFF_SC + 0] = floop;
        P[OFF_SC + 1] = fexit;
        P[OFF_SC + 2] = p0;
        P[OFF_SC + 3] = fexit * be * ep0;
        P[OFF_SC + 4] = fexit * be * ep1;
        P[OFF_SC + 5] = ep0;
        P[OFF_SC + 6] = ep1;
        P[OFF_SC + 7] = (1.0f - p0) * be * ep0;
        P[OFF_SC + 8] = (1.0f - p0) * be * ep1;
        P[OFF_SC + 9] = 1.0f - p0;
    }
    __syncthreads();

    // per-state (j = 0..511) padded coefficient arrays
    float en = beginp[j];
    if (j >= 1) en += mtdp[0] * expf(cplog[j - 1]) * dtmp[j - 1];
    P[OFF_ENTER + j] = en;
    P[OFF_MTM + j] = (j >= 1) ? mtmp[j - 1] : 0.f;
    P[OFF_I2M + j] = (j >= 1) ? i2mp[j - 1] : 0.f;
    P[OFF_DTM + j] = (j >= 1) ? dtmp[j - 1] : 0.f;
    P[OFF_WC  + j] = (j >= 1) ? mtdp[j]     : 0.f;
    P[OFF_MC  + j] = (j >= 1) ? dtdp[j - 1] : 0.f;
    P[OFF_M2I + j] = (j < 511) ? m2ip[j] : 0.f;
    P[OFF_I2I + j] = (j < 511) ? i2ip[j] : 0.f;
    P[OFF_M2E + j] = (j < 511)
        ? (m2ep[j] + mtdp[j + 1] * expf(cplog[511] - cplog[j + 1]))
        : 1.0f;

    // match emission softmax, written INTERLEAVED so the forward kernel's
    // column read is two conflict-free ds_read_b128:
    //   pos = half*256 + (state/8)*4 + (state%4), half = (state%8)/4
    {
        const float* row = em + j * 25;
        float mx = row[0];
        for (int s = 1; s < 25; ++s) mx = fmaxf(mx, row[s]);
        float sm = 0.f;
        for (int s = 0; s < 25; ++s) sm += expf(row[s] - mx);
        float inv = 1.0f / sm;
        int lanej = j >> 3, e = j & 7;
        int pos = ((e >> 2) << 8) | (lanej << 2) | (e & 3);
        for (int s = 0; s < 25; ++s)
            P[OFF_EMB + s * 512 + pos] = expf(row[s] - mx) * inv;
    }
}

// ---------------------------------------------------------------------------
// Forward: one wave per batch element. DPP affine scan (constant multipliers
// precomputed), emissions + seq staged in LDS, deferred norm every 8 steps.
// ---------------------------------------------------------------------------
__global__ __launch_bounds__(64, 1) void hmm_forward(
    const int* __restrict__ seq, const float* __restrict__ P,
    float* __restrict__ out)
{
    __shared__ __align__(16) float sEmb[25 * 512];
    __shared__ float sIns[32];
    __shared__ __align__(16) int sSeq[TLEN];

    const int lane = threadIdx.x;
    const int b = blockIdx.x;
    const int base = lane * 8;

    // ---- stage LDS: emission table (51200B), ins (25), seq (4KB) ----
    {
        const float4* src = (const float4*)(P + OFF_EMB);
        float4* dst = (float4*)sEmb;
#pragma unroll 5
        for (int k = lane; k < 25 * 128; k += 64) dst[k] = src[k];
        if (lane < 32) sIns[lane] = P[OFF_INS + (lane < 25 ? lane : 0)];
        const int4* s4 = (const int4*)(seq + b * TLEN);
        int4* d4 = (int4*)sSeq;
#pragma unroll
        for (int k = lane; k < 256; k += 64) d4[k] = s4[k];
    }

    // ---- per-lane constants ----
    float enter_[8], mtm_[8], i2m_[8], dtm_[8], wC_[8], mC_[8], m2i_[8], i2i_[8], m2e_[8];
#pragma unroll
    for (int e = 0; e < 8; ++e) {
        enter_[e] = P[OFF_ENTER + base + e];
        mtm_[e]   = P[OFF_MTM + base + e];
        i2m_[e]   = P[OFF_I2M + base + e];
        dtm_[e]   = P[OFF_DTM + base + e];
        wC_[e]    = P[OFF_WC + base + e];
        mC_[e]    = P[OFF_MC + base + e];
        m2i_[e]   = P[OFF_M2I + base + e];
        i2i_[e]   = P[OFF_I2I + base + e];
        m2e_[e]   = P[OFF_M2E + base + e];
    }
    const float floop = P[OFF_SC + 0], fexit = P[OFF_SC + 1], p0 = P[OFF_SC + 2];
    const float c1ep0 = P[OFF_SC + 3], c1ep1 = P[OFF_SC + 4];
    const float ep0 = P[OFF_SC + 5], ep1 = P[OFF_SC + 6];
    const float U0 = P[OFF_SC + 7], RF0 = P[OFF_SC + 8], omp0 = P[OFF_SC + 9];

    // local prefix multipliers (constant per lane)
    float Mpre[8];
    Mpre[0] = mC_[0];
#pragma unroll
    for (int e = 1; e < 8; ++e) Mpre[e] = Mpre[e - 1] * mC_[e];

    // per-stage scan multipliers (constant): M-side of the affine scan is
    // time-invariant, so precompute what round-1 recomputed every step.
    float MsK0, MsK1, MsK2, MsK3, MsK4, MsK5;
    {
        float Ms = Mpre[7], Mo;
        Mo = fdpp<0x111, 0xF>(1.f, Ms); MsK0 = Ms; Ms *= Mo;
        Mo = fdpp<0x112, 0xF>(1.f, Ms); MsK1 = Ms; Ms *= Mo;
        Mo = fdpp<0x114, 0xF>(1.f, Ms); MsK2 = Ms; Ms *= Mo;
        Mo = fdpp<0x118, 0xF>(1.f, Ms); MsK3 = Ms; Ms *= Mo;
        Mo = fdpp<0x142, 0xA>(1.f, Ms); MsK4 = Ms; Ms *= Mo;
        Mo = fdpp<0x143, 0xC>(1.f, Ms); MsK5 = Ms; Ms *= Mo;
    }

    __syncthreads();

    // ---- init at t=0 ----
    float EmA[8], EmB[8], EiA, EiB;
    int sym0 = sSeq[0];
    {
        const float4* c4 = (const float4*)(sEmb + (sym0 << 9) + (lane << 2));
        float4 xx = c4[0], yy = c4[64];
        EmA[0] = xx.x; EmA[1] = xx.y; EmA[2] = xx.z; EmA[3] = xx.w;
        EmA[4] = yy.x; EmA[5] = yy.y; EmA[6] = yy.z; EmA[7] = yy.w;
        EiA = sIns[sym0];
    }
    float am[8], ai[8];
#pragma unroll
    for (int e = 0; e < 8; ++e) { am[e] = EmA[e] * (omp0 * enter_[e]); ai[e] = 0.f; }
    float f0 = p0 * EiA;
    float U  = U0 * EiA;
    float RF = RF0 * EiA;
    float ll2 = 0.f;

    // prime pipeline: EmA <- E_1, symN <- s[2]
    int symN = sSeq[1];
    {
        const float4* c4 = (const float4*)(sEmb + (symN << 9) + (lane << 2));
        float4 xx = c4[0], yy = c4[64];
        EmA[0] = xx.x; EmA[1] = xx.y; EmA[2] = xx.z; EmA[3] = xx.w;
        EmA[4] = yy.x; EmA[5] = yy.y; EmA[6] = yy.z; EmA[7] = yy.w;
        EiA = sIns[symN];
    }
    symN = sSeq[2];

#define STEP(T, EmC, EiC, EmN, EiN)                                            \
  {                                                                            \
    { /* prefetch E_{T+1}; fetch s[T+2] */                                     \
      const float4* c4 = (const float4*)(sEmb + (symN << 9) + (lane << 2));    \
      float4 xx = c4[0], yy = c4[64];                                          \
      EmN[0] = xx.x; EmN[1] = xx.y; EmN[2] = xx.z; EmN[3] = xx.w;              \
      EmN[4] = yy.x; EmN[5] = yy.y; EmN[6] = yy.z; EmN[7] = yy.w;              \
      EiN = sIns[symN];                                                        \
      int tn = (T) + 2; tn = tn > TLEN - 1 ? TLEN - 1 : tn;                    \
      symN = sSeq[tn];                                                         \
    }                                                                          \
    float amL = fdpp<0x138, 0xF>(0.f, am[7]);                                  \
    float aiL = fdpp<0x138, 0xF>(0.f, ai[7]);                                  \
    /* local affine prefix for the delete chain */                             \
    float Apre[8];                                                             \
    Apre[0] = amL * wC_[0];                                                    \
    _Pragma("unroll")                                                          \
    for (int e = 1; e < 8; ++e)                                                \
      Apre[e] = fmaf(Apre[e - 1], mC_[e], am[e - 1] * wC_[e]);                 \
    /* cross-lane affine scan: 4x row_shr + bcast15 + bcast31, DPP only */     \
    float As = Apre[7];                                                        \
    As = fmaf(MsK0, fdpp<0x111, 0xF>(0.f, As), As);                            \
    As = fmaf(MsK1, fdpp<0x112, 0xF>(0.f, As), As);                            \
    As = fmaf(MsK2, fdpp<0x114, 0xF>(0.f, As), As);                            \
    As = fmaf(MsK3, fdpp<0x118, 0xF>(0.f, As), As);                            \
    As = fmaf(MsK4, fdpp<0x142, 0xA>(0.f, As), As);                            \
    As = fmaf(MsK5, fdpp<0x143, 0xC>(0.f, As), As);                            \
    float carry = fdpp<0x138, 0xF>(0.f, As);                                   \
    /* dsum = sum(a_m * m2e_tot) */                                            \
    float dl = am[0] * m2e_[0];                                                \
    _Pragma("unroll")                                                          \
    for (int e = 1; e < 8; ++e) dl = fmaf(am[e], m2e_[e], dl);                 \
    float dsum = bcast63(wave_sum_to63(dl));                                   \
    /* scalar states (replicated) */                                           \
    float aFU = (f0 + U) * fexit;                                              \
    float nf0 = EiC * (f0 * floop);                                            \
    float nU  = EiC * (fmaf(f0, c1ep0, U * (floop + c1ep0)) + dsum * ep0);     \
    float nRF = EiC * ((f0 + U) * c1ep1 + dsum * ep1 + RF * floop);            \
    f0 = nf0; U = nU; RF = nRF;                                                \
    /* fused insert+match update, descending keeps old values live */          \
    _Pragma("unroll")                                                          \
    for (int e = 7; e >= 1; --e) {                                             \
      float iin = ai[e - 1] * i2m_[e];                                         \
      ai[e] = EiC * fmaf(am[e], m2i_[e], ai[e] * i2i_[e]);                     \
      float Qp = fmaf(Mpre[e - 1], carry, Apre[e - 1]);                        \
      float infl = fmaf(aFU, enter_[e],                                        \
                   fmaf(am[e - 1], mtm_[e], fmaf(dtm_[e], Qp, iin)));          \
      am[e] = EmC[e] * infl;                                                   \
    }                                                                          \
    {                                                                          \
      float iin = aiL * i2m_[0];                                               \
      ai[0] = EiC * fmaf(am[0], m2i_[0], ai[0] * i2i_[0]);                     \
      float infl = fmaf(aFU, enter_[0],                                        \
                   fmaf(amL, mtm_[0], fmaf(dtm_[0], carry, iin)));             \
      am[0] = EmC[0] * infl;                                                   \
    }                                                                          \
    /* deferred normalization every 8 steps (f0/U/RF counted ONCE now) */      \
    if (((T) & 7) == 0 || (T) == TLEN - 1) {                                   \
      float sl = (lane == 0) ? (f0 + U + RF) : 0.f;                            \
      _Pragma("unroll")                                                        \
      for (int e = 0; e < 8; ++e) sl += am[e] + ai[e];                         \
      float s = bcast63(wave_sum_to63(sl)) + TINY_F;                           \
      ll2 += __log2f(s);                                                       \
      float inv = 1.0f / s;                                                    \
      _Pragma("unroll")                                                        \
      for (int e = 0; e < 8; ++e) { am[e] *= inv; ai[e] *= inv; }              \
      f0 *= inv; U *= inv; RF *= inv;                                          \
    }                                                                          \
  }

    for (int t = 1; t < TLEN - 1; t += 2) {
        STEP(t, EmA, EiA, EmB, EiB);
        STEP(t + 1, EmB, EiB, EmA, EiA);
    }
    STEP(TLEN - 1, EmA, EiA, EmB, EiB);
#undef STEP

    if (lane == 0) out[b] = ll2 * 0.69314718055994530942f;
}

extern "C" void kernel_launch(void* const* d_in, const int* in_sizes, int n_in,
                              void* d_out, int out_size, void* d_ws, size_t ws_size,
                              hipStream_t stream) {
    const int*   seq   = (const int*)d_in[0];
    const float* em    = (const float*)d_in[1];
    const float* ins   = (const float*)d_in[2];
    const float* flank = (const float*)d_in[3];
    const float* btm   = (const float*)d_in[4];
    const float* m2e   = (const float*)d_in[5];
    const float* mtm   = (const float*)d_in[6];
    const float* m2i   = (const float*)d_in[7];
    const float* i2m   = (const float*)d_in[8];
    const float* i2i   = (const float*)d_in[9];
    const float* mtd   = (const float*)d_in[10];
    const float* dtm   = (const float*)d_in[11];
    const float* dtd   = (const float*)d_in[12];
    const float* lfl   = (const float*)d_in[13];
    const float* lfe   = (const float*)d_in[14];
    const float* e2u   = (const float*)d_in[15];
    const float* e2r   = (const float*)d_in[16];
    const float* e2t   = (const float*)d_in[17];
    float* P = (float*)d_ws;  // needs 71680 B
    float* out = (float*)d_out;

    hipLaunchKernelGGL(hmm_setup, dim3(1), dim3(512), 0, stream,
        em, ins, flank, btm, m2e, mtm, m2i, i2m, i2i, mtd, dtm, dtd,
        lfl, lfe, e2u, e2r, e2t, P);
    hipLaunchKernelGGL(hmm_forward, dim3(128), dim3(64), 0, stream, seq, P, out);
}